// Round 8
// baseline (1852.416 us; speedup 1.0000x reference)
//
#include <hip/hip_runtime.h>

// Problem dims
#define Bdim 64
#define Sdim 512
#define Vdim 30000
#define Edim 300
#define Hdim 256
#define Cdim 32
#define G4   1024     // 4*H
#define NROW 32768    // B*S
#define KQ   32       // 256 k-values / 8 per 16B chunk
#define USTAGE 9      // kq-blocks of U staged in DYNAMIC LDS (144 KB)
#define RKQ    20     // kq-blocks of U in VGPRs via VOLATILE asm loads
                      // (plain loads were remat-sunk by the scheduler in
                      //  r3/r6/r7 — attributes alone never stopped it)
#define EPAIR  (Edim / 2)   // 150 f16-pairs along E
#define XLSTR  152          // padded LDS row stride (uints) for 8B alignment

// ---------- f16 helpers (store as plain ushort to avoid ABI surprises) -----
typedef _Float16 half2v __attribute__((ext_vector_type(2)));
typedef unsigned int u32x4 __attribute__((ext_vector_type(4)));

__device__ __forceinline__ unsigned short f2h_bits(float f) {
    union { _Float16 h; unsigned short u; } v; v.h = (_Float16)f; return v.u;
}
__device__ __forceinline__ float h2f(unsigned short u) {
    union { _Float16 h; unsigned short u; } v; v.u = u; return (float)v.h;
}
__device__ __forceinline__ unsigned int pack2h(float lo, float hi) {
    return (unsigned int)f2h_bits(lo) | ((unsigned int)f2h_bits(hi) << 16);
}
__device__ __forceinline__ float sigf(float x) { return 1.0f / (1.0f + __expf(-x)); }
__device__ __forceinline__ float tanhfast(float x) { return 2.0f / (1.0f + __expf(-2.0f * x)) - 1.0f; }

// 2 MACs from packed f16 pairs, f32 accumulate (v_dot2_f32_f16 when available)
__device__ __forceinline__ float dot2(unsigned int u, unsigned int h, float acc) {
#if __has_builtin(__builtin_amdgcn_fdot2)
    union { unsigned int i; half2v h; } a, b; a.i = u; b.i = h;
    return __builtin_amdgcn_fdot2(a.h, b.h, acc, false);
#else
    acc = fmaf(h2f((unsigned short)(u & 0xffffu)), h2f((unsigned short)(h & 0xffffu)), acc);
    return fmaf(h2f((unsigned short)(u >> 16)), h2f((unsigned short)(h >> 16)), acc);
#endif
}
// 8 MACs from one 16B U chunk and one 16B h chunk (two independent chains)
__device__ __forceinline__ void dot8(float& a0, float& a1, u32x4 uv, u32x4 hv) {
    a0 = dot2(uv.x, hv.x, a0);
    a1 = dot2(uv.y, hv.y, a1);
    a0 = dot2(uv.z, hv.z, a0);
    a1 = dot2(uv.w, hv.w, a1);
}

// ---------- K0a: pack U (f32 [256][1024]) -> f16 chunks [2][32][1024][8] ----
__global__ __launch_bounds__(256) void k_pack_u8(
    const float* __restrict__ Uf, const float* __restrict__ Ub,
    unsigned short* __restrict__ upk8)
{
    int idx = blockIdx.x * 256 + threadIdx.x;   // 0 .. 65535
    if (idx >= 2 * KQ * 1024) return;
    int dir = idx >> 15;
    int rem = idx & 32767;
    int kq  = rem >> 10;
    int n   = rem & 1023;
    const float* U = dir ? Ub : Uf;
    unsigned int w[4];
    #pragma unroll
    for (int p = 0; p < 4; ++p)
        w[p] = pack2h(U[(8 * kq + 2 * p) * G4 + n], U[(8 * kq + 2 * p + 1) * G4 + n]);
    uint4 o = make_uint4(w[0], w[1], w[2], w[3]);
    *(uint4*)&upk8[(size_t)idx * 8] = o;
}

// ---------- K0b: pack emb f32 [V][300] -> f16 pairs [V*150] uints -----------
__global__ __launch_bounds__(256) void k_pack_emb(
    const float* __restrict__ emb, unsigned int* __restrict__ embp)
{
    int p = blockIdx.x * 256 + threadIdx.x;     // flat pair index
    if (p >= Vdim * EPAIR) return;
    float2 v = *(const float2*)&emb[(size_t)2 * p];
    embp[p] = pack2h(v.x, v.y);
}

// ---------- K0c: pack W f32 [300][1024] -> f16 k-pairs [2][150][1024] -------
__global__ __launch_bounds__(256) void k_pack_w(
    const float* __restrict__ Wf, const float* __restrict__ Wb,
    unsigned int* __restrict__ Wp)
{
    int idx = blockIdx.x * 256 + threadIdx.x;   // 0 .. 2*150*1024-1
    if (idx >= 2 * EPAIR * 1024) return;
    int dir = idx / (EPAIR * 1024);
    int rem = idx - dir * (EPAIR * 1024);
    int kp  = rem >> 10;
    int n   = rem & 1023;
    const float* W = dir ? Wb : Wf;
    Wp[idx] = pack2h(W[(2 * kp) * G4 + n], W[(2 * kp + 1) * G4 + n]);
}

// ---------- K1: xproj = emb[tokens] @ W + bias  -> f16 [2][NROW][1024] ------
// grid (NROW/32, 8), block 256. BOTH dirs per block. Each thread owns 4
// CONSECUTIVE cols -> W reads are dwordx4, stores are ushort4.
__global__ __launch_bounds__(256) void k_xproj(
    const int* __restrict__ tokens, const unsigned int* __restrict__ embp,
    const unsigned int* __restrict__ Wp,
    const float* __restrict__ bf_, const float* __restrict__ bb_,
    unsigned short* __restrict__ xp)
{
    __shared__ unsigned int xl[32 * XLSTR];    // 19456 B, f16 pairs
    const int m0  = blockIdx.x * 32;
    const int tid = threadIdx.x;

    for (int i = tid; i < 32 * EPAIR; i += 256) {
        int r = i / EPAIR, kp = i - r * EPAIR;
        int tok = tokens[m0 + r];
        xl[r * XLSTR + kp] = embp[(size_t)tok * EPAIR + kp];
    }
    __syncthreads();

    const int tx = tid & 31, ty = tid >> 5;          // ty: 8 groups of 4 rows
    const int c0 = blockIdx.y * 128 + tx * 4;        // 4 consecutive cols
    float bj[2][4];
    #pragma unroll
    for (int j = 0; j < 4; ++j) {
        bj[0][j] = bf_[c0 + j];
        bj[1][j] = bb_[c0 + j];
    }
    float acc[2][4][4] = {};

    for (int kp = 0; kp < EPAIR; kp += 2) {          // 150 = 75*2 exact
        uint2 xv[4];
        #pragma unroll
        for (int i = 0; i < 4; ++i)
            xv[i] = *(const uint2*)&xl[(ty * 4 + i) * XLSTR + kp];
        #pragma unroll
        for (int kk = 0; kk < 2; ++kk) {
            #pragma unroll
            for (int d = 0; d < 2; ++d) {
                uint4 wv = *(const uint4*)(Wp + (size_t)d * EPAIR * 1024
                                              + (size_t)(kp + kk) * 1024 + c0);
                #pragma unroll
                for (int i = 0; i < 4; ++i) {
                    unsigned int xpair = kk ? xv[i].y : xv[i].x;
                    acc[d][i][0] = dot2(wv.x, xpair, acc[d][i][0]);
                    acc[d][i][1] = dot2(wv.y, xpair, acc[d][i][1]);
                    acc[d][i][2] = dot2(wv.z, xpair, acc[d][i][2]);
                    acc[d][i][3] = dot2(wv.w, xpair, acc[d][i][3]);
                }
            }
        }
    }
    #pragma unroll
    for (int d = 0; d < 2; ++d) {
        size_t base = (size_t)d * NROW * G4;
        #pragma unroll
        for (int i = 0; i < 4; ++i) {
            size_t row = (size_t)(m0 + ty * 4 + i) * G4;
            ushort4 o;
            o.x = f2h_bits(acc[d][i][0] + bj[d][0]);
            o.y = f2h_bits(acc[d][i][1] + bj[d][1]);
            o.z = f2h_bits(acc[d][i][2] + bj[d][2]);
            o.w = f2h_bits(acc[d][i][3] + bj[d][3]);
            *(ushort4*)&xp[base + row + c0] = o;
        }
    }
}

// ---------- K2: LSTM recurrence, v9 ----------------------------------------
// 128 WGs = (dir, batch), 1024 threads, 1 WG/CU (LDS-capped => 4 waves/EU,
// declared via waves_per_eu so the VGPR budget is 128).
// U kq-blocks: [0,9) in 144KB dynamic LDS, [9,29) in VGPRs via VOLATILE asm
// loads (non-rematerializable => scheduler cannot sink them), 3 streamed.
// Serial n<256 tail (r7's parallel tail cost +0.18us/step — reverted).
__global__ __launch_bounds__(1024)
__attribute__((amdgpu_waves_per_eu(4, 4)))
void k_lstm(
    const unsigned short* __restrict__ upk8,   // [2][KQ][1024][8] f16
    const unsigned short* __restrict__ xp,     // [2][NROW][1024]  f16
    unsigned short* __restrict__ hout)         // [NROW][512] f16 = [hf|hb]
{
    const int bx  = blockIdx.x;
    const int dir = bx >> 6;
    const int b   = bx & 63;
    const int n   = threadIdx.x;               // 0..1023
    const int gi  = n >> 8;                    // gate: 0=i 1=f 2=g 3=o
    const unsigned short* __restrict__ Uq = upk8 + (size_t)dir * (KQ * 1024 * 8);
    const unsigned short* __restrict__ xpd =
        xp + (size_t)dir * NROW * G4 + (size_t)b * Sdim * G4;

    __shared__ float          abuf[1024];                   // 4 KB gates
    __shared__ __align__(16) unsigned short hl[256];        // f16 h
    extern __shared__ __align__(16) unsigned short ust[];   // 144 KB (kq 0..8)

    {   // vectorized one-time LDS stage of U kq-blocks [0,USTAGE)
        const u32x4* src = (const u32x4*)Uq;
        u32x4*       dst = (u32x4*)ust;
        for (int i = n; i < USTAGE * 1024; i += 1024) dst[i] = src[i];
    }
    // register-stage U kq-blocks [USTAGE, USTAGE+RKQ) — step-invariant.
    // VOLATILE asm loads: cannot be rematerialized/sunk into the step loop.
    u32x4 ur[RKQ];
    #pragma unroll
    for (int r = 0; r < RKQ; ++r) {
        const unsigned short* p = Uq + ((size_t)(USTAGE + r) * 1024 + n) * 8;
        asm volatile("global_load_dwordx4 %0, %1, off"
                     : "=v"(ur[r]) : "v"(p) : "memory");
    }
    asm volatile("s_waitcnt vmcnt(0)" ::: "memory");

    if (n < 256) hl[n] = 0;
    float c = 0.0f;
    __syncthreads();

    for (int step = 0; step < Sdim; ++step) {
        const int t = dir ? (Sdim - 1 - step) : step;
        float zx = h2f(xpd[(size_t)t * G4 + n]);   // issued early, used late
        float a0 = 0.0f, a1 = 0.0f;
        // streamed-from-L2 blocks (issue loads first; compiler pipelines)
        #pragma unroll
        for (int kq = USTAGE + RKQ; kq < KQ; ++kq) {
            u32x4 uv = *(const u32x4*)&Uq[((size_t)kq * 1024 + n) * 8];
            u32x4 hv = *(const u32x4*)&hl[kq * 8];
            dot8(a0, a1, uv, hv);
        }
        // register-staged blocks
        #pragma unroll
        for (int r = 0; r < RKQ; ++r) {
            u32x4 hv = *(const u32x4*)&hl[(USTAGE + r) * 8];
            dot8(a0, a1, ur[r], hv);
        }
        // LDS-staged blocks
        #pragma unroll
        for (int kq = 0; kq < USTAGE; ++kq) {
            u32x4 uv = *(const u32x4*)&ust[(kq * 1024 + n) * 8];
            u32x4 hv = *(const u32x4*)&hl[kq * 8];
            dot8(a0, a1, uv, hv);
        }
        float z = zx + a0 + a1;
        float a = (gi == 2) ? tanhfast(z) : sigf(z);
        abuf[n] = a;
        __syncthreads();               // abuf complete; all hl readers done
        if (n < 256) {
            float iv = abuf[n];
            float fv = abuf[n + 256];
            float gv = abuf[n + 512];
            float ov = abuf[n + 768];
            c = fv * c + iv * gv;
            float hn = ov * tanhfast(c);
            unsigned short hb = f2h_bits(hn);
            hl[n] = hb;
            hout[((size_t)(b * Sdim + t)) * 512 + dir * 256 + n] = hb;
        }
        __syncthreads();               // hl ready for next step
    }
}

// ---------- K3: logits = [hf|hb] @ Wd + bd -> d_out[0:1048576] --------------
__global__ __launch_bounds__(256) void k_dense(
    const unsigned short* __restrict__ hall, const float* __restrict__ Wd,
    const float* __restrict__ bd, float* __restrict__ outL)
{
    __shared__ float wl[256 * 32];    // 32 KB
    __shared__ float hlr[8 * 512];    // 16 KB
    const int r0  = blockIdx.x * 8;
    const int tid = threadIdx.x;
    for (int i = tid; i < 8 * 512; i += 256)
        hlr[i] = h2f(hall[(size_t)r0 * 512 + i]);
    const int tx = tid & 31, ty = tid >> 5;
    float acc = 0.0f;
    for (int half = 0; half < 2; ++half) {
        __syncthreads();   // prior readers done (also covers hlr stores)
        for (int i = tid; i < 256 * 32; i += 256) wl[i] = Wd[half * 8192 + i];
        __syncthreads();
        const float* hrow = hlr + ty * 512 + half * 256;
        #pragma unroll 8
        for (int k = 0; k < 256; ++k)
            acc = fmaf(hrow[k], wl[k * 32 + tx], acc);
    }
    outL[(size_t)(r0 + ty) * 32 + tx] = acc + bd[tx];
}

// ---------- K4: CRF log-likelihood + trans passthrough ----------------------
// Scan chains split into 4 independent partials (ILP).
__global__ __launch_bounds__(256) void k_crf(
    const float* __restrict__ logits, const int* __restrict__ targets,
    const int* __restrict__ lengths, const float* __restrict__ trans,
    float* __restrict__ out_ll, float* __restrict__ out_trans)
{
    const int b   = blockIdx.x;
    const int tid = threadIdx.x;
    __shared__ float tT[32 * 33];     // trans transposed, padded
    __shared__ float alpha[32];
    __shared__ float red[2][256];

    if (b == 0)
        for (int i = tid; i < 1024; i += 256) out_trans[i] = trans[i];
    for (int i = tid; i < 1024; i += 256) {
        int ii = i >> 5, jj = i & 31;
        tT[jj * 33 + ii] = trans[i];
    }
    const int len = lengths[b];
    const float* lg = logits + (size_t)b * Sdim * Cdim;
    const int*   tg = targets + b * Sdim;

    float u = 0.0f, bs = 0.0f;
    for (int t = tid; t < Sdim; t += 256) {
        if (t < len) {
            u += lg[t * 32 + tg[t]];
            if (t >= 1) bs += trans[tg[t - 1] * 32 + tg[t]];
        }
    }
    red[0][tid] = u; red[1][tid] = bs;
    __syncthreads();
    for (int off = 128; off > 0; off >>= 1) {
        if (tid < off) {
            red[0][tid] += red[0][tid + off];
            red[1][tid] += red[1][tid + off];
        }
        __syncthreads();
    }

    if (tid < 32) alpha[tid] = lg[tid];
    float trow[32];
    if (tid < 32) {
        #pragma unroll
        for (int i = 0; i < 32; ++i) trow[i] = tT[tid * 33 + i];
    }
    __syncthreads();

    float lcur = 0.0f;
    if (tid < 32 && len > 1) lcur = lg[32 + tid];
    for (int t = 1; t < len; ++t) {
        float nv = 0.0f, lnxt = 0.0f;
        if (tid < 32) {
            if (t + 1 < len) lnxt = lg[(t + 1) * 32 + tid];   // prefetch
            float v[32];
            #pragma unroll
            for (int i = 0; i < 32; ++i) v[i] = alpha[i] + trow[i];
            float m0 = v[0], m1 = v[1], m2 = v[2], m3 = v[3];
            #pragma unroll
            for (int i = 4; i < 32; i += 4) {
                m0 = fmaxf(m0, v[i]);
                m1 = fmaxf(m1, v[i + 1]);
                m2 = fmaxf(m2, v[i + 2]);
                m3 = fmaxf(m3, v[i + 3]);
            }
            float m = fmaxf(fmaxf(m0, m1), fmaxf(m2, m3));
            float s0 = 0.0f, s1 = 0.0f, s2 = 0.0f, s3 = 0.0f;
            #pragma unroll
            for (int i = 0; i < 32; i += 4) {
                s0 += __expf(v[i] - m);
                s1 += __expf(v[i + 1] - m);
                s2 += __expf(v[i + 2] - m);
                s3 += __expf(v[i + 3] - m);
            }
            nv = m + __logf((s0 + s1) + (s2 + s3)) + lcur;
        }
        __syncthreads();
        if (tid < 32) alpha[tid] = nv;
        __syncthreads();
        lcur = lnxt;
    }
    if (tid == 0) {
        float m = -3.0e38f;
        for (int jj = 0; jj < 32; ++jj) m = fmaxf(m, alpha[jj]);
        float s = 0.0f;
        for (int jj = 0; jj < 32; ++jj) s += __expf(alpha[jj] - m);
        out_ll[b] = red[0][0] + red[1][0] - (m + __logf(s));
    }
}

// ---------------------------------------------------------------------------
extern "C" void kernel_launch(void* const* d_in, const int* in_sizes, int n_in,
                              void* d_out, int out_size, void* d_ws, size_t ws_size,
                              hipStream_t stream) {
    (void)in_sizes; (void)n_in; (void)out_size; (void)ws_size;
    const int*   tokens  = (const int*)d_in[0];
    const int*   lengths = (const int*)d_in[1];
    const int*   targets = (const int*)d_in[2];
    const float* emb     = (const float*)d_in[3];
    const float* Wf      = (const float*)d_in[4];
    const float* Uf      = (const float*)d_in[5];
    const float* bf_     = (const float*)d_in[6];
    const float* Wb      = (const float*)d_in[7];
    const float* Ub      = (const float*)d_in[8];
    const float* bb_     = (const float*)d_in[9];
    const float* Wd      = (const float*)d_in[10];
    const float* bd      = (const float*)d_in[11];
    const float* trans   = (const float*)d_in[12];

    float* out_logits = (float*)d_out;                 // 1048576
    float* out_ll     = out_logits + 1048576;          // 64
    float* out_trans  = out_ll + 64;                   // 1024

    // ws layout (~161 MiB, unchanged):
    //   [0, 1MB)              ushort upk8[2][32][1024][8]   (f16 U chunks)
    //   [1MB, 1MB+128MB)      ushort xp [2][NROW][1024]     (f16)
    //   [.., +32MB)           ushort hall[NROW][512]        (f16)
    // embp (18MB) + Wp (1.2MB) live INSIDE the hall region.
    char* ws = (char*)d_ws;
    unsigned short* upk8 = (unsigned short*)ws;
    unsigned short* xp   = (unsigned short*)(ws + (1u << 20));
    char*           hreg = ws + (1u << 20) + (size_t)2 * NROW * G4 * 2;
    unsigned short* hall = (unsigned short*)hreg;
    unsigned int*   embp = (unsigned int*)hreg;                       // 18.0 MB
    unsigned int*   Wp   = (unsigned int*)(hreg + (size_t)Vdim * EPAIR * 4); // 1.2 MB

    const size_t lstm_dyn_lds = (size_t)USTAGE * 1024 * 8 * 2;        // 147456 B

    k_pack_u8 <<<dim3(256), dim3(256), 0, stream>>>(Uf, Ub, upk8);
    k_pack_emb<<<dim3((Vdim * EPAIR + 255) / 256), dim3(256), 0, stream>>>(emb, embp);
    k_pack_w  <<<dim3((2 * EPAIR * 1024 + 255) / 256), dim3(256), 0, stream>>>(Wf, Wb, Wp);
    k_xproj   <<<dim3(NROW / 32, 8), dim3(256), 0, stream>>>(tokens, embp, Wp, bf_, bb_, xp);
    k_lstm    <<<dim3(128), dim3(1024), lstm_dyn_lds, stream>>>(upk8, xp, hall);
    k_dense   <<<dim3(NROW / 8), dim3(256), 0, stream>>>(hall, Wd, bd, out_logits);
    k_crf     <<<dim3(64), dim3(256), 0, stream>>>(out_logits, targets, lengths, trans, out_ll, out_trans);
}

// Round 9
// 1430.956 us; speedup vs baseline: 1.2945x; 1.2945x over previous
//
#include <hip/hip_runtime.h>

// Problem dims
#define Bdim 64
#define Sdim 512
#define Vdim 30000
#define Edim 300
#define Hdim 256
#define Cdim 32
#define G4   1024     // 4*H
#define NROW 32768    // B*S
#define KQ   32       // 256 k-values / 8 per 16B chunk
#define USTAGE 9      // kq-blocks of U staged in DYNAMIC LDS (144 KB)
#define RKQ    12     // kq-blocks of U in VGPRs (r5-proven; >64-VGPR path is
                      // closed: r3 sink, r4 scratch-spill, r6/r7 attrs ignored,
                      // r8 volatile->AGPR shuffle all failed)
#define EPAIR  (Edim / 2)   // 150 f16-pairs along E
#define XLSTR  152          // padded LDS row stride (uints) for 8B alignment

// ---------- f16 helpers (store as plain ushort to avoid ABI surprises) -----
typedef _Float16 half2v __attribute__((ext_vector_type(2)));
typedef unsigned int u32x4 __attribute__((ext_vector_type(4)));

__device__ __forceinline__ unsigned short f2h_bits(float f) {
    union { _Float16 h; unsigned short u; } v; v.h = (_Float16)f; return v.u;
}
__device__ __forceinline__ float h2f(unsigned short u) {
    union { _Float16 h; unsigned short u; } v; v.u = u; return (float)v.h;
}
__device__ __forceinline__ unsigned int pack2h(float lo, float hi) {
    return (unsigned int)f2h_bits(lo) | ((unsigned int)f2h_bits(hi) << 16);
}
__device__ __forceinline__ float sigf(float x) { return 1.0f / (1.0f + __expf(-x)); }
__device__ __forceinline__ float tanhfast(float x) { return 2.0f / (1.0f + __expf(-2.0f * x)) - 1.0f; }

// 2 MACs from packed f16 pairs, f32 accumulate (v_dot2_f32_f16 when available)
__device__ __forceinline__ float dot2(unsigned int u, unsigned int h, float acc) {
#if __has_builtin(__builtin_amdgcn_fdot2)
    union { unsigned int i; half2v h; } a, b; a.i = u; b.i = h;
    return __builtin_amdgcn_fdot2(a.h, b.h, acc, false);
#else
    acc = fmaf(h2f((unsigned short)(u & 0xffffu)), h2f((unsigned short)(h & 0xffffu)), acc);
    return fmaf(h2f((unsigned short)(u >> 16)), h2f((unsigned short)(h >> 16)), acc);
#endif
}
// 8 MACs from one 16B U chunk and one 16B h chunk (two independent chains)
__device__ __forceinline__ void dot8(float& a0, float& a1, u32x4 uv, u32x4 hv) {
    a0 = dot2(uv.x, hv.x, a0);
    a1 = dot2(uv.y, hv.y, a1);
    a0 = dot2(uv.z, hv.z, a0);
    a1 = dot2(uv.w, hv.w, a1);
}

// ---------- K0a: pack U (f32 [256][1024]) -> f16 chunks [2][32][1024][8] ----
__global__ __launch_bounds__(256) void k_pack_u8(
    const float* __restrict__ Uf, const float* __restrict__ Ub,
    unsigned short* __restrict__ upk8)
{
    int idx = blockIdx.x * 256 + threadIdx.x;   // 0 .. 65535
    if (idx >= 2 * KQ * 1024) return;
    int dir = idx >> 15;
    int rem = idx & 32767;
    int kq  = rem >> 10;
    int n   = rem & 1023;
    const float* U = dir ? Ub : Uf;
    unsigned int w[4];
    #pragma unroll
    for (int p = 0; p < 4; ++p)
        w[p] = pack2h(U[(8 * kq + 2 * p) * G4 + n], U[(8 * kq + 2 * p + 1) * G4 + n]);
    uint4 o = make_uint4(w[0], w[1], w[2], w[3]);
    *(uint4*)&upk8[(size_t)idx * 8] = o;
}

// ---------- K0b: pack emb f32 [V][300] -> f16 pairs [V*150] uints -----------
__global__ __launch_bounds__(256) void k_pack_emb(
    const float* __restrict__ emb, unsigned int* __restrict__ embp)
{
    int p = blockIdx.x * 256 + threadIdx.x;     // flat pair index
    if (p >= Vdim * EPAIR) return;
    float2 v = *(const float2*)&emb[(size_t)2 * p];
    embp[p] = pack2h(v.x, v.y);
}

// ---------- K0c: pack W f32 [300][1024] -> f16 k-pairs [2][150][1024] -------
__global__ __launch_bounds__(256) void k_pack_w(
    const float* __restrict__ Wf, const float* __restrict__ Wb,
    unsigned int* __restrict__ Wp)
{
    int idx = blockIdx.x * 256 + threadIdx.x;   // 0 .. 2*150*1024-1
    if (idx >= 2 * EPAIR * 1024) return;
    int dir = idx / (EPAIR * 1024);
    int rem = idx - dir * (EPAIR * 1024);
    int kp  = rem >> 10;
    int n   = rem & 1023;
    const float* W = dir ? Wb : Wf;
    Wp[idx] = pack2h(W[(2 * kp) * G4 + n], W[(2 * kp + 1) * G4 + n]);
}

// ---------- K0d: pack Wd f32 [512][32] -> f16 k-pairs [256][32] uints -------
// Launched AFTER k_lstm into the then-dead upk8 region (32 KB).
__global__ __launch_bounds__(256) void k_pack_wd(
    const float* __restrict__ Wd, unsigned int* __restrict__ WdP)
{
    int i = blockIdx.x * 256 + threadIdx.x;     // kp*32 + c
    if (i >= 256 * 32) return;
    int kp = i >> 5, c = i & 31;
    WdP[i] = pack2h(Wd[(2 * kp) * 32 + c], Wd[(2 * kp + 1) * 32 + c]);
}

// ---------- K1: xproj = emb[tokens] @ W + bias  -> f16 [2][NROW][1024] ------
// grid (NROW/32, 8), block 256. BOTH dirs per block. Each thread owns 4
// CONSECUTIVE cols -> W reads are dwordx4, stores are ushort4.
__global__ __launch_bounds__(256) void k_xproj(
    const int* __restrict__ tokens, const unsigned int* __restrict__ embp,
    const unsigned int* __restrict__ Wp,
    const float* __restrict__ bf_, const float* __restrict__ bb_,
    unsigned short* __restrict__ xp)
{
    __shared__ unsigned int xl[32 * XLSTR];    // 19456 B, f16 pairs
    const int m0  = blockIdx.x * 32;
    const int tid = threadIdx.x;

    for (int i = tid; i < 32 * EPAIR; i += 256) {
        int r = i / EPAIR, kp = i - r * EPAIR;
        int tok = tokens[m0 + r];
        xl[r * XLSTR + kp] = embp[(size_t)tok * EPAIR + kp];
    }
    __syncthreads();

    const int tx = tid & 31, ty = tid >> 5;          // ty: 8 groups of 4 rows
    const int c0 = blockIdx.y * 128 + tx * 4;        // 4 consecutive cols
    float bj[2][4];
    #pragma unroll
    for (int j = 0; j < 4; ++j) {
        bj[0][j] = bf_[c0 + j];
        bj[1][j] = bb_[c0 + j];
    }
    float acc[2][4][4] = {};

    for (int kp = 0; kp < EPAIR; kp += 2) {          // 150 = 75*2 exact
        uint2 xv[4];
        #pragma unroll
        for (int i = 0; i < 4; ++i)
            xv[i] = *(const uint2*)&xl[(ty * 4 + i) * XLSTR + kp];
        #pragma unroll
        for (int kk = 0; kk < 2; ++kk) {
            #pragma unroll
            for (int d = 0; d < 2; ++d) {
                uint4 wv = *(const uint4*)(Wp + (size_t)d * EPAIR * 1024
                                              + (size_t)(kp + kk) * 1024 + c0);
                #pragma unroll
                for (int i = 0; i < 4; ++i) {
                    unsigned int xpair = kk ? xv[i].y : xv[i].x;
                    acc[d][i][0] = dot2(wv.x, xpair, acc[d][i][0]);
                    acc[d][i][1] = dot2(wv.y, xpair, acc[d][i][1]);
                    acc[d][i][2] = dot2(wv.z, xpair, acc[d][i][2]);
                    acc[d][i][3] = dot2(wv.w, xpair, acc[d][i][3]);
                }
            }
        }
    }
    #pragma unroll
    for (int d = 0; d < 2; ++d) {
        size_t base = (size_t)d * NROW * G4;
        #pragma unroll
        for (int i = 0; i < 4; ++i) {
            size_t row = (size_t)(m0 + ty * 4 + i) * G4;
            ushort4 o;
            o.x = f2h_bits(acc[d][i][0] + bj[d][0]);
            o.y = f2h_bits(acc[d][i][1] + bj[d][1]);
            o.z = f2h_bits(acc[d][i][2] + bj[d][2]);
            o.w = f2h_bits(acc[d][i][3] + bj[d][3]);
            *(ushort4*)&xp[base + row + c0] = o;
        }
    }
}

// ---------- K2: LSTM recurrence (r5-proven form) ----------------------------
// 128 WGs = (dir, batch), 1024 threads (16 waves/CU). Thread n owns column n.
// U kq-blocks: [0,9) in 144KB DYNAMIC LDS, [9,21) in VGPRs (RKQ=12),
// remaining 11 streamed from L2 (176 KB/step). Serial n<256 tail.
__global__ __launch_bounds__(1024) void k_lstm(
    const unsigned short* __restrict__ upk8,   // [2][KQ][1024][8] f16
    const unsigned short* __restrict__ xp,     // [2][NROW][1024]  f16
    unsigned short* __restrict__ hout)         // [NROW][512] f16 = [hf|hb]
{
    const int bx  = blockIdx.x;
    const int dir = bx >> 6;
    const int b   = bx & 63;
    const int n   = threadIdx.x;               // 0..1023
    const int gi  = n >> 8;                    // gate: 0=i 1=f 2=g 3=o
    const unsigned short* __restrict__ Uq = upk8 + (size_t)dir * (KQ * 1024 * 8);
    const unsigned short* __restrict__ xpd =
        xp + (size_t)dir * NROW * G4 + (size_t)b * Sdim * G4;

    __shared__ float          abuf[1024];                   // 4 KB gates
    __shared__ __align__(16) unsigned short hl[256];        // f16 h
    extern __shared__ __align__(16) unsigned short ust[];   // 144 KB (kq 0..8)

    {   // vectorized one-time LDS stage of U kq-blocks [0,USTAGE)
        const u32x4* src = (const u32x4*)Uq;
        u32x4*       dst = (u32x4*)ust;
        for (int i = n; i < USTAGE * 1024; i += 1024) dst[i] = src[i];
    }
    // register-stage U kq-blocks [USTAGE, USTAGE+RKQ) — step-invariant
    u32x4 ur[RKQ];
    #pragma unroll
    for (int r = 0; r < RKQ; ++r)
        ur[r] = *(const u32x4*)&Uq[((size_t)(USTAGE + r) * 1024 + n) * 8];

    if (n < 256) hl[n] = 0;
    float c = 0.0f;
    __syncthreads();

    for (int step = 0; step < Sdim; ++step) {
        const int t = dir ? (Sdim - 1 - step) : step;
        float zx = h2f(xpd[(size_t)t * G4 + n]);   // issued early, used late
        float a0 = 0.0f, a1 = 0.0f;
        // streamed-from-L2 blocks (issue loads first; compiler pipelines)
        #pragma unroll
        for (int kq = USTAGE + RKQ; kq < KQ; ++kq) {
            u32x4 uv = *(const u32x4*)&Uq[((size_t)kq * 1024 + n) * 8];
            u32x4 hv = *(const u32x4*)&hl[kq * 8];
            dot8(a0, a1, uv, hv);
        }
        // register-staged blocks
        #pragma unroll
        for (int r = 0; r < RKQ; ++r) {
            u32x4 hv = *(const u32x4*)&hl[(USTAGE + r) * 8];
            dot8(a0, a1, ur[r], hv);
        }
        // LDS-staged blocks
        #pragma unroll
        for (int kq = 0; kq < USTAGE; ++kq) {
            u32x4 uv = *(const u32x4*)&ust[(kq * 1024 + n) * 8];
            u32x4 hv = *(const u32x4*)&hl[kq * 8];
            dot8(a0, a1, uv, hv);
        }
        float z = zx + a0 + a1;
        float a = (gi == 2) ? tanhfast(z) : sigf(z);
        abuf[n] = a;
        __syncthreads();               // abuf complete; all hl readers done
        if (n < 256) {
            float iv = abuf[n];
            float fv = abuf[n + 256];
            float gv = abuf[n + 512];
            float ov = abuf[n + 768];
            c = fv * c + iv * gv;
            float hn = ov * tanhfast(c);
            unsigned short hb = f2h_bits(hn);
            hl[n] = hb;
            hout[((size_t)(b * Sdim + t)) * 512 + dir * 256 + n] = hb;
        }
        __syncthreads();               // hl ready for next step
    }
}

// ---------- K3: logits = [hf|hb] @ Wd + bd, f16 dot2 form -------------------
// grid 4096, block 256 = 8 rows x 32 cols. WdP (f16 k-pairs) fits LDS once,
// transposed [col][kpair] (pad 260 => 16B-aligned rows). h rows as f16 pairs.
// 128 LDS instr/thread (was 1024), 256 dot2 (was 512 fma).
__global__ __launch_bounds__(256) void k_dense(
    const unsigned short* __restrict__ hall, const unsigned int* __restrict__ WdP,
    const float* __restrict__ bd, float* __restrict__ outL)
{
    __shared__ unsigned int wlT[32 * 260];   // 33.3 KB, [c][kp]
    __shared__ unsigned int hu[8 * 256];     // 8 KB,    [r][kp]
    const int r0  = blockIdx.x * 8;
    const int tid = threadIdx.x;

    for (int i = tid; i < 256 * 32; i += 256) {
        int kp = i >> 5, c = i & 31;
        wlT[c * 260 + kp] = WdP[i];
    }
    const unsigned int* hsrc = (const unsigned int*)(hall + (size_t)r0 * 512);
    for (int i = tid; i < 8 * 256; i += 256) hu[i] = hsrc[i];
    __syncthreads();

    const int tx = tid & 31, ty = tid >> 5;
    float a0 = 0.0f, a1 = 0.0f;
    #pragma unroll 8
    for (int kp = 0; kp < 256; kp += 4) {
        u32x4 hv = *(const u32x4*)&hu[ty * 256 + kp];      // broadcast per row
        u32x4 wv = *(const u32x4*)&wlT[tx * 260 + kp];
        a0 = dot2(wv.x, hv.x, a0);
        a1 = dot2(wv.y, hv.y, a1);
        a0 = dot2(wv.z, hv.z, a0);
        a1 = dot2(wv.w, hv.w, a1);
    }
    outL[(size_t)(r0 + ty) * 32 + tx] = a0 + a1 + bd[tx];
}

// ---------- K4: CRF log-likelihood, single-wave blocks ----------------------
// grid 64, block 64 (ONE wave: barriers free). Scan: lane=(j,half) — each
// half reduces 16 sources, one shfl_xor(32) combines. Butterfly reductions.
__global__ __launch_bounds__(64) void k_crf(
    const float* __restrict__ logits, const int* __restrict__ targets,
    const int* __restrict__ lengths, const float* __restrict__ trans,
    float* __restrict__ out_ll, float* __restrict__ out_trans)
{
    const int b    = blockIdx.x;
    const int lane = threadIdx.x;          // 0..63
    __shared__ __align__(16) float alpha[32];

    if (b == 0)
        for (int i = lane; i < 1024; i += 64) out_trans[i] = trans[i];

    const int len = lengths[b];
    const float* lg = logits + (size_t)b * Sdim * Cdim;
    const int*   tg = targets + b * Sdim;

    // unary + binary sums over t (64 threads), wave butterfly reduce
    float ub = 0.0f;
    for (int t = lane; t < Sdim; t += 64) {
        if (t < len) {
            ub += lg[t * 32 + tg[t]];
            if (t >= 1) ub += trans[tg[t - 1] * 32 + tg[t]];
        }
    }
    #pragma unroll
    for (int m = 32; m >= 1; m >>= 1) ub += __shfl_xor(ub, m);

    const int j = lane & 31, half = lane >> 5;
    float trow16[16];                      // trans[i][j], i in half*16..+15
    #pragma unroll
    for (int q = 0; q < 16; ++q) trow16[q] = trans[(half * 16 + q) * 32 + j];

    if (lane < 32) alpha[lane] = lg[lane];
    __syncthreads();

    float lcur = (len > 1) ? lg[32 + j] : 0.0f;
    for (int t = 1; t < len; ++t) {
        float lnxt = (t + 1 < len) ? lg[(t + 1) * 32 + j] : 0.0f;   // prefetch
        float v[16];
        #pragma unroll
        for (int q = 0; q < 16; ++q) v[q] = alpha[half * 16 + q] + trow16[q];
        float m0 = v[0], m1 = v[1], m2 = v[2], m3 = v[3];
        #pragma unroll
        for (int q = 4; q < 16; q += 4) {
            m0 = fmaxf(m0, v[q]);
            m1 = fmaxf(m1, v[q + 1]);
            m2 = fmaxf(m2, v[q + 2]);
            m3 = fmaxf(m3, v[q + 3]);
        }
        float ml = fmaxf(fmaxf(m0, m1), fmaxf(m2, m3));
        float m  = fmaxf(ml, __shfl_xor(ml, 32));
        float s0 = 0.0f, s1 = 0.0f, s2 = 0.0f, s3 = 0.0f;
        #pragma unroll
        for (int q = 0; q < 16; q += 4) {
            s0 += __expf(v[q] - m);
            s1 += __expf(v[q + 1] - m);
            s2 += __expf(v[q + 2] - m);
            s3 += __expf(v[q + 3] - m);
        }
        float sl = (s0 + s1) + (s2 + s3);
        float s  = sl + __shfl_xor(sl, 32);
        float nv = m + __logf(s) + lcur;
        __syncthreads();
        if (lane < 32) alpha[lane] = nv;
        __syncthreads();
        lcur = lnxt;
    }
    if (lane == 0) {
        float m = -3.0e38f;
        for (int q = 0; q < 32; ++q) m = fmaxf(m, alpha[q]);
        float s = 0.0f;
        for (int q = 0; q < 32; ++q) s += __expf(alpha[q] - m);
        out_ll[b] = ub - (m + __logf(s));
    }
}

// ---------------------------------------------------------------------------
extern "C" void kernel_launch(void* const* d_in, const int* in_sizes, int n_in,
                              void* d_out, int out_size, void* d_ws, size_t ws_size,
                              hipStream_t stream) {
    (void)in_sizes; (void)n_in; (void)out_size; (void)ws_size;
    const int*   tokens  = (const int*)d_in[0];
    const int*   lengths = (const int*)d_in[1];
    const int*   targets = (const int*)d_in[2];
    const float* emb     = (const float*)d_in[3];
    const float* Wf      = (const float*)d_in[4];
    const float* Uf      = (const float*)d_in[5];
    const float* bf_     = (const float*)d_in[6];
    const float* Wb      = (const float*)d_in[7];
    const float* Ub      = (const float*)d_in[8];
    const float* bb_     = (const float*)d_in[9];
    const float* Wd      = (const float*)d_in[10];
    const float* bd      = (const float*)d_in[11];
    const float* trans   = (const float*)d_in[12];

    float* out_logits = (float*)d_out;                 // 1048576
    float* out_ll     = out_logits + 1048576;          // 64
    float* out_trans  = out_ll + 64;                   // 1024

    // ws layout (~161 MiB, unchanged):
    //   [0, 1MB)              ushort upk8[2][32][1024][8]   (f16 U chunks)
    //   [1MB, 1MB+128MB)      ushort xp [2][NROW][1024]     (f16)
    //   [.., +32MB)           ushort hall[NROW][512]        (f16)
    // embp (18MB) + Wp (1.2MB) live INSIDE the hall region (dead after xproj).
    // WdP (32KB) reuses the upk8 region (dead after k_lstm).
    char* ws = (char*)d_ws;
    unsigned short* upk8 = (unsigned short*)ws;
    unsigned short* xp   = (unsigned short*)(ws + (1u << 20));
    char*           hreg = ws + (1u << 20) + (size_t)2 * NROW * G4 * 2;
    unsigned short* hall = (unsigned short*)hreg;
    unsigned int*   embp = (unsigned int*)hreg;                       // 18.0 MB
    unsigned int*   Wp   = (unsigned int*)(hreg + (size_t)Vdim * EPAIR * 4); // 1.2 MB
    unsigned int*   WdP  = (unsigned int*)ws;                         // after lstm

    const size_t lstm_dyn_lds = (size_t)USTAGE * 1024 * 8 * 2;        // 147456 B

    k_pack_u8 <<<dim3(256), dim3(256), 0, stream>>>(Uf, Ub, upk8);
    k_pack_emb<<<dim3((Vdim * EPAIR + 255) / 256), dim3(256), 0, stream>>>(emb, embp);
    k_pack_w  <<<dim3((2 * EPAIR * 1024 + 255) / 256), dim3(256), 0, stream>>>(Wf, Wb, Wp);
    k_xproj   <<<dim3(NROW / 32, 8), dim3(256), 0, stream>>>(tokens, embp, Wp, bf_, bb_, xp);
    k_lstm    <<<dim3(128), dim3(1024), lstm_dyn_lds, stream>>>(upk8, xp, hall);
    k_pack_wd <<<dim3(32), dim3(256), 0, stream>>>(Wd, WdP);
    k_dense   <<<dim3(NROW / 8), dim3(256), 0, stream>>>(hall, WdP, bd, out_logits);
    k_crf     <<<dim3(64), dim3(64), 0, stream>>>(out_logits, targets, lengths, trans, out_ll, out_trans);
}

// Round 10
// 1179.383 us; speedup vs baseline: 1.5707x; 1.2133x over previous
//
#include <hip/hip_runtime.h>

// Problem dims
#define Bdim 64
#define Sdim 512
#define Vdim 30000
#define Edim 300
#define Hdim 256
#define Cdim 32
#define G4   1024     // 4*H
#define NROW 32768    // B*S
#define KQ   32       // 256 k-values / 8 per 16B chunk
#define USTAGE 9      // kq-blocks of U staged in DYNAMIC LDS (144 KB)
#define RKQ    12     // kq-blocks of U in VGPRs (r5-proven; >64-VGPR path is
                      // closed for the 1024-thr dyn-LDS lstm: r3/r4/r6/r7/r8)
#define EPAIR  (Edim / 2)   // 150 f16-pairs along E
#define KCH    5            // xproj K-chunks of 32 pairs (150 -> 5*32, zero-pad)

// ---------- f16 helpers (store as plain ushort to avoid ABI surprises) -----
typedef _Float16 half2v __attribute__((ext_vector_type(2)));
typedef _Float16 f16x8  __attribute__((ext_vector_type(8)));
typedef float    f32x4  __attribute__((ext_vector_type(4)));
typedef unsigned int u32x4 __attribute__((ext_vector_type(4)));

__device__ __forceinline__ unsigned short f2h_bits(float f) {
    union { _Float16 h; unsigned short u; } v; v.h = (_Float16)f; return v.u;
}
__device__ __forceinline__ float h2f(unsigned short u) {
    union { _Float16 h; unsigned short u; } v; v.u = u; return (float)v.h;
}
__device__ __forceinline__ unsigned int pack2h(float lo, float hi) {
    return (unsigned int)f2h_bits(lo) | ((unsigned int)f2h_bits(hi) << 16);
}
__device__ __forceinline__ float sigf(float x) { return 1.0f / (1.0f + __expf(-x)); }
__device__ __forceinline__ float tanhfast(float x) { return 2.0f / (1.0f + __expf(-2.0f * x)) - 1.0f; }

// 2 MACs from packed f16 pairs, f32 accumulate (v_dot2_f32_f16 when available)
__device__ __forceinline__ float dot2(unsigned int u, unsigned int h, float acc) {
#if __has_builtin(__builtin_amdgcn_fdot2)
    union { unsigned int i; half2v h; } a, b; a.i = u; b.i = h;
    return __builtin_amdgcn_fdot2(a.h, b.h, acc, false);
#else
    acc = fmaf(h2f((unsigned short)(u & 0xffffu)), h2f((unsigned short)(h & 0xffffu)), acc);
    return fmaf(h2f((unsigned short)(u >> 16)), h2f((unsigned short)(h >> 16)), acc);
#endif
}
// 8 MACs from one 16B U chunk and one 16B h chunk (two independent chains)
__device__ __forceinline__ void dot8(float& a0, float& a1, u32x4 uv, u32x4 hv) {
    a0 = dot2(uv.x, hv.x, a0);
    a1 = dot2(uv.y, hv.y, a1);
    a0 = dot2(uv.z, hv.z, a0);
    a1 = dot2(uv.w, hv.w, a1);
}

// ---------- K0a: pack U (f32 [256][1024]) -> f16 chunks [2][32][1024][8] ----
__global__ __launch_bounds__(256) void k_pack_u8(
    const float* __restrict__ Uf, const float* __restrict__ Ub,
    unsigned short* __restrict__ upk8)
{
    int idx = blockIdx.x * 256 + threadIdx.x;   // 0 .. 65535
    if (idx >= 2 * KQ * 1024) return;
    int dir = idx >> 15;
    int rem = idx & 32767;
    int kq  = rem >> 10;
    int n   = rem & 1023;
    const float* U = dir ? Ub : Uf;
    unsigned int w[4];
    #pragma unroll
    for (int p = 0; p < 4; ++p)
        w[p] = pack2h(U[(8 * kq + 2 * p) * G4 + n], U[(8 * kq + 2 * p + 1) * G4 + n]);
    uint4 o = make_uint4(w[0], w[1], w[2], w[3]);
    *(uint4*)&upk8[(size_t)idx * 8] = o;
}

// ---------- K0b: pack emb f32 [V][300] -> f16 pairs [V*150] uints -----------
__global__ __launch_bounds__(256) void k_pack_emb(
    const float* __restrict__ emb, unsigned int* __restrict__ embp)
{
    int p = blockIdx.x * 256 + threadIdx.x;     // flat pair index
    if (p >= Vdim * EPAIR) return;
    float2 v = *(const float2*)&emb[(size_t)2 * p];
    embp[p] = pack2h(v.x, v.y);
}

// ---------- K0c: pack W f32 [300][1024] -> f16 k-pairs [2][150][1024] -------
__global__ __launch_bounds__(256) void k_pack_w(
    const float* __restrict__ Wf, const float* __restrict__ Wb,
    unsigned int* __restrict__ Wp)
{
    int idx = blockIdx.x * 256 + threadIdx.x;   // 0 .. 2*150*1024-1
    if (idx >= 2 * EPAIR * 1024) return;
    int dir = idx / (EPAIR * 1024);
    int rem = idx - dir * (EPAIR * 1024);
    int kp  = rem >> 10;
    int n   = rem & 1023;
    const float* W = dir ? Wb : Wf;
    Wp[idx] = pack2h(W[(2 * kp) * G4 + n], W[(2 * kp + 1) * G4 + n]);
}

// ---------- K0d: pack Wd f32 [512][32] -> f16 k-pairs [256][32] uints -------
__global__ __launch_bounds__(256) void k_pack_wd(
    const float* __restrict__ Wd, unsigned int* __restrict__ WdP)
{
    int i = blockIdx.x * 256 + threadIdx.x;     // kp*32 + c
    if (i >= 256 * 32) return;
    int kp = i >> 5, c = i & 31;
    WdP[i] = pack2h(Wd[(2 * kp) * 32 + c], Wd[(2 * kp + 1) * 32 + c]);
}

// ---------- K1: xproj via MFMA ----------------------------------------------
// xp[dir] = emb[tokens] (f16) @ W[dir] (f16) + bias : [32768 x 300]*[300 x 1024]
// grid (512, 8, 2) : M-tile 64, N-tile 128, per-dir. block 256 = 4 waves (2x2).
// K chunked 5 x 64 (zero-padded 300->320). A,B staged in LDS with +8 f16 row
// pad (144 B stride = 9*16B: aligned b128 frag reads, 2-way banks = free).
// mfma_f32_16x16x32_f16; C/D layout col=lane&15, row=(lane>>4)*4+reg (m89).
__global__ __launch_bounds__(256, 4) void k_xproj(
    const int* __restrict__ tokens, const unsigned int* __restrict__ embp,
    const unsigned int* __restrict__ Wp,
    const float* __restrict__ bf_, const float* __restrict__ bb_,
    unsigned short* __restrict__ xp)
{
    __shared__ unsigned short As[64][72];   // [m][k]  9.2 KB
    __shared__ unsigned short Bs[128][72];  // [n][k] 18.4 KB
    __shared__ int tokL[64];

    const int m0  = blockIdx.x * 64;
    const int n0  = blockIdx.y * 128;
    const int dir = blockIdx.z;
    const unsigned int* W = Wp + (size_t)dir * EPAIR * 1024;
    const float* bias = dir ? bb_ : bf_;
    const int tid = threadIdx.x;

    if (tid < 64) tokL[tid] = tokens[m0 + tid];
    __syncthreads();

    const int w    = tid >> 6;          // wave 0..3
    const int wm   = w >> 1;            // 0..1 (m-half, 32 rows)
    const int wn   = w & 1;             // 0..1 (n-half, 64 cols)
    const int lane = tid & 63;
    const int lr   = lane & 15;
    const int lh   = lane >> 4;         // 0..3

    f32x4 acc[2][4] = {};               // [mt][nt]

    // preload bias for the 4 n-tiles this wave owns (col fixed per nt)
    float bv[4];
    #pragma unroll
    for (int nt = 0; nt < 4; ++nt)
        bv[nt] = bias[n0 + wn * 64 + nt * 16 + lr];

    for (int kc = 0; kc < KCH; ++kc) {
        const int k0p = kc * 32;        // base k-pair of this chunk
        if (kc) __syncthreads();        // prior compute done before restage

        // stage A: 64 rows x 32 pairs. thread: row=tid>>2, 8 pairs.
        {
            const int r  = tid >> 2;
            const int jb = (tid & 3) * 8;
            const int tok = tokL[r];
            unsigned int* dst = (unsigned int*)&As[r][0];
            #pragma unroll
            for (int q = 0; q < 8; ++q) {
                int gp = k0p + jb + q;
                dst[jb + q] = (gp < EPAIR) ? embp[(size_t)tok * EPAIR + gp] : 0u;
            }
        }
        // stage B (transposed): 128 cols x 32 pairs.
        {
            #pragma unroll
            for (int q = 0; q < 16; ++q) {
                int ii = q * 256 + tid;
                int jp = ii >> 7;           // 0..31
                int c  = ii & 127;
                int gp = k0p + jp;
                unsigned int v = (gp < EPAIR) ? W[(size_t)gp * 1024 + n0 + c] : 0u;
                ((unsigned int*)&Bs[c][0])[jp] = v;
            }
        }
        __syncthreads();

        // fragments + MFMA
        f16x8 a[2][2];
        #pragma unroll
        for (int mt = 0; mt < 2; ++mt)
            #pragma unroll
            for (int ks = 0; ks < 2; ++ks)
                a[mt][ks] = *(const f16x8*)&As[wm * 32 + mt * 16 + lr][ks * 32 + lh * 8];
        #pragma unroll
        for (int nt = 0; nt < 4; ++nt) {
            f16x8 b0 = *(const f16x8*)&Bs[wn * 64 + nt * 16 + lr][lh * 8];
            f16x8 b1 = *(const f16x8*)&Bs[wn * 64 + nt * 16 + lr][32 + lh * 8];
            #pragma unroll
            for (int mt = 0; mt < 2; ++mt) {
                acc[mt][nt] = __builtin_amdgcn_mfma_f32_16x16x32_f16(a[mt][0], b0, acc[mt][nt], 0, 0, 0);
                acc[mt][nt] = __builtin_amdgcn_mfma_f32_16x16x32_f16(a[mt][1], b1, acc[mt][nt], 0, 0, 0);
            }
        }
    }

    // epilogue: D lane mapping col=lane&15, row=(lane>>4)*4+reg
    size_t base = (size_t)dir * NROW * G4;
    #pragma unroll
    for (int mt = 0; mt < 2; ++mt) {
        #pragma unroll
        for (int nt = 0; nt < 4; ++nt) {
            int col = n0 + wn * 64 + nt * 16 + lr;
            #pragma unroll
            for (int rr = 0; rr < 4; ++rr) {
                int row = m0 + wm * 32 + mt * 16 + lh * 4 + rr;
                xp[base + (size_t)row * G4 + col] = f2h_bits(acc[mt][nt][rr] + bv[nt]);
            }
        }
    }
}

// ---------- K2: LSTM recurrence (r5-proven form) ----------------------------
// 128 WGs = (dir, batch), 1024 threads (16 waves/CU). Thread n owns column n.
// U kq-blocks: [0,9) in 144KB DYNAMIC LDS, [9,21) in VGPRs (RKQ=12),
// remaining 11 streamed from L2 (176 KB/step). Serial n<256 tail.
__global__ __launch_bounds__(1024) void k_lstm(
    const unsigned short* __restrict__ upk8,   // [2][KQ][1024][8] f16
    const unsigned short* __restrict__ xp,     // [2][NROW][1024]  f16
    unsigned short* __restrict__ hout)         // [NROW][512] f16 = [hf|hb]
{
    const int bx  = blockIdx.x;
    const int dir = bx >> 6;
    const int b   = bx & 63;
    const int n   = threadIdx.x;               // 0..1023
    const int gi  = n >> 8;                    // gate: 0=i 1=f 2=g 3=o
    const unsigned short* __restrict__ Uq = upk8 + (size_t)dir * (KQ * 1024 * 8);
    const unsigned short* __restrict__ xpd =
        xp + (size_t)dir * NROW * G4 + (size_t)b * Sdim * G4;

    __shared__ float          abuf[1024];                   // 4 KB gates
    __shared__ __align__(16) unsigned short hl[256];        // f16 h
    extern __shared__ __align__(16) unsigned short ust[];   // 144 KB (kq 0..8)

    {   // vectorized one-time LDS stage of U kq-blocks [0,USTAGE)
        const u32x4* src = (const u32x4*)Uq;
        u32x4*       dst = (u32x4*)ust;
        for (int i = n; i < USTAGE * 1024; i += 1024) dst[i] = src[i];
    }
    // register-stage U kq-blocks [USTAGE, USTAGE+RKQ) — step-invariant
    u32x4 ur[RKQ];
    #pragma unroll
    for (int r = 0; r < RKQ; ++r)
        ur[r] = *(const u32x4*)&Uq[((size_t)(USTAGE + r) * 1024 + n) * 8];

    if (n < 256) hl[n] = 0;
    float c = 0.0f;
    __syncthreads();

    for (int step = 0; step < Sdim; ++step) {
        const int t = dir ? (Sdim - 1 - step) : step;
        float zx = h2f(xpd[(size_t)t * G4 + n]);   // issued early, used late
        float a0 = 0.0f, a1 = 0.0f;
        // streamed-from-L2 blocks (issue loads first; compiler pipelines)
        #pragma unroll
        for (int kq = USTAGE + RKQ; kq < KQ; ++kq) {
            u32x4 uv = *(const u32x4*)&Uq[((size_t)kq * 1024 + n) * 8];
            u32x4 hv = *(const u32x4*)&hl[kq * 8];
            dot8(a0, a1, uv, hv);
        }
        // register-staged blocks
        #pragma unroll
        for (int r = 0; r < RKQ; ++r) {
            u32x4 hv = *(const u32x4*)&hl[(USTAGE + r) * 8];
            dot8(a0, a1, ur[r], hv);
        }
        // LDS-staged blocks
        #pragma unroll
        for (int kq = 0; kq < USTAGE; ++kq) {
            u32x4 uv = *(const u32x4*)&ust[(kq * 1024 + n) * 8];
            u32x4 hv = *(const u32x4*)&hl[kq * 8];
            dot8(a0, a1, uv, hv);
        }
        float z = zx + a0 + a1;
        float a = (gi == 2) ? tanhfast(z) : sigf(z);
        abuf[n] = a;
        __syncthreads();               // abuf complete; all hl readers done
        if (n < 256) {
            float iv = abuf[n];
            float fv = abuf[n + 256];
            float gv = abuf[n + 512];
            float ov = abuf[n + 768];
            c = fv * c + iv * gv;
            float hn = ov * tanhfast(c);
            unsigned short hb = f2h_bits(hn);
            hl[n] = hb;
            hout[((size_t)(b * Sdim + t)) * 512 + dir * 256 + n] = hb;
        }
        __syncthreads();               // hl ready for next step
    }
}

// ---------- K3: logits = [hf|hb] @ Wd + bd, f16 dot2 form -------------------
__global__ __launch_bounds__(256) void k_dense(
    const unsigned short* __restrict__ hall, const unsigned int* __restrict__ WdP,
    const float* __restrict__ bd, float* __restrict__ outL)
{
    __shared__ unsigned int wlT[32 * 260];   // 33.3 KB, [c][kp]
    __shared__ unsigned int hu[8 * 256];     // 8 KB,    [r][kp]
    const int r0  = blockIdx.x * 8;
    const int tid = threadIdx.x;

    for (int i = tid; i < 256 * 32; i += 256) {
        int kp = i >> 5, c = i & 31;
        wlT[c * 260 + kp] = WdP[i];
    }
    const unsigned int* hsrc = (const unsigned int*)(hall + (size_t)r0 * 512);
    for (int i = tid; i < 8 * 256; i += 256) hu[i] = hsrc[i];
    __syncthreads();

    const int tx = tid & 31, ty = tid >> 5;
    float a0 = 0.0f, a1 = 0.0f;
    #pragma unroll 8
    for (int kp = 0; kp < 256; kp += 4) {
        u32x4 hv = *(const u32x4*)&hu[ty * 256 + kp];      // broadcast per row
        u32x4 wv = *(const u32x4*)&wlT[tx * 260 + kp];
        a0 = dot2(wv.x, hv.x, a0);
        a1 = dot2(wv.y, hv.y, a1);
        a0 = dot2(wv.z, hv.z, a0);
        a1 = dot2(wv.w, hv.w, a1);
    }
    outL[(size_t)(r0 + ty) * 32 + tx] = a0 + a1 + bd[tx];
}

// ---------- K4: CRF log-likelihood, single-wave blocks ----------------------
__global__ __launch_bounds__(64) void k_crf(
    const float* __restrict__ logits, const int* __restrict__ targets,
    const int* __restrict__ lengths, const float* __restrict__ trans,
    float* __restrict__ out_ll, float* __restrict__ out_trans)
{
    const int b    = blockIdx.x;
    const int lane = threadIdx.x;          // 0..63
    __shared__ __align__(16) float alpha[32];

    if (b == 0)
        for (int i = lane; i < 1024; i += 64) out_trans[i] = trans[i];

    const int len = lengths[b];
    const float* lg = logits + (size_t)b * Sdim * Cdim;
    const int*   tg = targets + b * Sdim;

    float ub = 0.0f;
    for (int t = lane; t < Sdim; t += 64) {
        if (t < len) {
            ub += lg[t * 32 + tg[t]];
            if (t >= 1) ub += trans[tg[t - 1] * 32 + tg[t]];
        }
    }
    #pragma unroll
    for (int m = 32; m >= 1; m >>= 1) ub += __shfl_xor(ub, m);

    const int j = lane & 31, half = lane >> 5;
    float trow16[16];
    #pragma unroll
    for (int q = 0; q < 16; ++q) trow16[q] = trans[(half * 16 + q) * 32 + j];

    if (lane < 32) alpha[lane] = lg[lane];
    __syncthreads();

    float lcur = (len > 1) ? lg[32 + j] : 0.0f;
    for (int t = 1; t < len; ++t) {
        float lnxt = (t + 1 < len) ? lg[(t + 1) * 32 + j] : 0.0f;   // prefetch
        float v[16];
        #pragma unroll
        for (int q = 0; q < 16; ++q) v[q] = alpha[half * 16 + q] + trow16[q];
        float m0 = v[0], m1 = v[1], m2 = v[2], m3 = v[3];
        #pragma unroll
        for (int q = 4; q < 16; q += 4) {
            m0 = fmaxf(m0, v[q]);
            m1 = fmaxf(m1, v[q + 1]);
            m2 = fmaxf(m2, v[q + 2]);
            m3 = fmaxf(m3, v[q + 3]);
        }
        float ml = fmaxf(fmaxf(m0, m1), fmaxf(m2, m3));
        float m  = fmaxf(ml, __shfl_xor(ml, 32));
        float s0 = 0.0f, s1 = 0.0f, s2 = 0.0f, s3 = 0.0f;
        #pragma unroll
        for (int q = 0; q < 16; q += 4) {
            s0 += __expf(v[q] - m);
            s1 += __expf(v[q + 1] - m);
            s2 += __expf(v[q + 2] - m);
            s3 += __expf(v[q + 3] - m);
        }
        float sl = (s0 + s1) + (s2 + s3);
        float s  = sl + __shfl_xor(sl, 32);
        float nv = m + __logf(s) + lcur;
        __syncthreads();
        if (lane < 32) alpha[lane] = nv;
        __syncthreads();
        lcur = lnxt;
    }
    if (lane == 0) {
        float m = -3.0e38f;
        for (int q = 0; q < 32; ++q) m = fmaxf(m, alpha[q]);
        float s = 0.0f;
        for (int q = 0; q < 32; ++q) s += __expf(alpha[q] - m);
        out_ll[b] = ub - (m + __logf(s));
    }
}

// ---------------------------------------------------------------------------
extern "C" void kernel_launch(void* const* d_in, const int* in_sizes, int n_in,
                              void* d_out, int out_size, void* d_ws, size_t ws_size,
                              hipStream_t stream) {
    (void)in_sizes; (void)n_in; (void)out_size; (void)ws_size;
    const int*   tokens  = (const int*)d_in[0];
    const int*   lengths = (const int*)d_in[1];
    const int*   targets = (const int*)d_in[2];
    const float* emb     = (const float*)d_in[3];
    const float* Wf      = (const float*)d_in[4];
    const float* Uf      = (const float*)d_in[5];
    const float* bf_     = (const float*)d_in[6];
    const float* Wb      = (const float*)d_in[7];
    const float* Ub      = (const float*)d_in[8];
    const float* bb_     = (const float*)d_in[9];
    const float* Wd      = (const float*)d_in[10];
    const float* bd      = (const float*)d_in[11];
    const float* trans   = (const float*)d_in[12];

    float* out_logits = (float*)d_out;                 // 1048576
    float* out_ll     = out_logits + 1048576;          // 64
    float* out_trans  = out_ll + 64;                   // 1024

    // ws layout (~161 MiB, unchanged):
    //   [0, 1MB)              ushort upk8[2][32][1024][8]   (f16 U chunks)
    //   [1MB, 1MB+128MB)      ushort xp [2][NROW][1024]     (f16)
    //   [.., +32MB)           ushort hall[NROW][512]        (f16)
    // embp (18MB) + Wp (1.2MB) live INSIDE the hall region (dead after xproj).
    // WdP (32KB) reuses the upk8 region (dead after k_lstm).
    char* ws = (char*)d_ws;
    unsigned short* upk8 = (unsigned short*)ws;
    unsigned short* xp   = (unsigned short*)(ws + (1u << 20));
    char*           hreg = ws + (1u << 20) + (size_t)2 * NROW * G4 * 2;
    unsigned short* hall = (unsigned short*)hreg;
    unsigned int*   embp = (unsigned int*)hreg;                       // 18.0 MB
    unsigned int*   Wp   = (unsigned int*)(hreg + (size_t)Vdim * EPAIR * 4); // 1.2 MB
    unsigned int*   WdP  = (unsigned int*)ws;                         // after lstm

    const size_t lstm_dyn_lds = (size_t)USTAGE * 1024 * 8 * 2;        // 147456 B

    k_pack_u8 <<<dim3(256), dim3(256), 0, stream>>>(Uf, Ub, upk8);
    k_pack_emb<<<dim3((Vdim * EPAIR + 255) / 256), dim3(256), 0, stream>>>(emb, embp);
    k_pack_w  <<<dim3((2 * EPAIR * 1024 + 255) / 256), dim3(256), 0, stream>>>(Wf, Wb, Wp);
    k_xproj   <<<dim3(NROW / 64, 8, 2), dim3(256), 0, stream>>>(tokens, embp, Wp, bf_, bb_, xp);
    k_lstm    <<<dim3(128), dim3(1024), lstm_dyn_lds, stream>>>(upk8, xp, hall);
    k_pack_wd <<<dim3(32), dim3(256), 0, stream>>>(Wd, WdP);
    k_dense   <<<dim3(NROW / 8), dim3(256), 0, stream>>>(hall, WdP, bd, out_logits);
    k_crf     <<<dim3(64), dim3(64), 0, stream>>>(out_logits, targets, lengths, trans, out_ll, out_trans);
}